// Round 10
// baseline (72.319 us; speedup 1.0000x reference)
//
#include <hip/hip_runtime.h>
#include <math.h>

#define SEQ   3000
#define FDIM  64
// 999 sequential steps = 111 groups (g0..g110) x 9 steps.
// CHANNEL-PARALLEL (R9) + chain-shortening: carry g=gelu(a); s_t = g_t + u_t
// is formed off-chain for the store, and W·u+q folds into qeff (computed from
// prefetched u, off the critical path). Critical chain per step:
//   g -> dpp -> fma -> fma -> dd -> rcp -> c01 -> p -> p -> pr -> fma  (10 deps)
// XCD-pair swizzle: the two blocks sharing each 128B cache line are mapped to
// blockIdx values equal mod 8 -> same XCD L2 -> no double HBM fetch.

#define PPW  0.23164189f                  // 0.3275911 / sqrt(2)
#define B1c  0.127414796f                 // 0.5*0.254829592
#define B2c  (-0.142248368f)              // 0.5*-0.284496736
#define B3c  0.7107068705f                // 0.5*1.421413741
#define B4c  (-0.7265760135f)             // 0.5*-1.453152027
#define B5c  0.5307027145f                // 0.5*1.061405429
#define NL2E (-0.72134752044448170368f)   // -0.5*log2(e)

// quad_perm ctrl: perm[0] | perm[1]<<2 | perm[2]<<4 | perm[3]<<6
// DPP1: lane p <- ch(p+1 mod 3), lane3 mirrors lane2: [1,2,0,0] = 9
// DPP2: lane p <- ch(p+2 mod 3), lane3 mirrors lane2: [2,0,1,1] = 82
#define DPPI(srci, ctrl)                                                      \
    __builtin_amdgcn_update_dpp(0, (srci), (ctrl), 0xf, 0xf, false)

#define DECL9(p) float p##0,p##1,p##2,p##3,p##4,p##5,p##6,p##7,p##8
#define TOUCH9(P) "+v"(P##0),"+v"(P##1),"+v"(P##2),"+v"(P##3),"+v"(P##4),     \
    "+v"(P##5),"+v"(P##6),"+v"(P##7),"+v"(P##8)

#define PF1(dst, p, OFF)                                                      \
    asm volatile("global_load_dword %0, %1, off offset:" #OFF                 \
                 : "=v"(dst) : "v"(p) : "memory")
#define ST1(val, p, OFF)                                                      \
    asm volatile("global_store_dword %0, %1, off offset:" #OFF                \
                 :: "v"(p), "v"(val) : "memory")

// 9 loads of one group for this lane's channel: rows 3t+3+p, stride 3 rows
// (768 B); xc bumps 9 rows (2304 B) per 3 loads so immediates stay < 4096.
#define PF9(P) do {                                                           \
    PF1(P##0, xc, 0); PF1(P##1, xc, 768); PF1(P##2, xc, 1536);                \
    xc += 9 * FDIM;                                                           \
    PF1(P##3, xc, 0); PF1(P##4, xc, 768); PF1(P##5, xc, 1536);                \
    xc += 9 * FDIM;                                                           \
    PF1(P##6, xc, 0); PF1(P##7, xc, 768); PF1(P##8, xc, 1536);                \
    xc += 9 * FDIM;                                                           \
} while (0)

// counted wait: P = load buffer about to be consumed (dataflow tie, rule #18)
#define WAITVM(Nlit, P) do {                                                  \
    asm volatile("s_waitcnt vmcnt(" #Nlit ")" : TOUCH9(P) : : "memory");      \
    __builtin_amdgcn_sched_barrier(0);                                        \
} while (0)

// One chain-step. Carried: gc (gelu output; s_0 at t=0), qe (= q + W·u_prev).
// Off-chain work (qn from u, z from exp path, relu, s-store) fills stalls.
#define GSTEP(F, u) do {                                                      \
    /* next qeff from this step's u (independent of state chain) */           \
    int ui_ = __builtin_bit_cast(int, u);                                     \
    float ud1_ = __builtin_bit_cast(float, DPPI(ui_, 9));                     \
    float ud2_ = __builtin_bit_cast(float, DPPI(ui_, 82));                    \
    float qn_ = fmaf(wA, u, q);                                               \
    qn_ = fmaf(wB, ud1_, qn_);                                                \
    qn_ = fmaf(wC, ud2_, qn_);                                                \
    /* critical chain */                                                      \
    int gi_ = __builtin_bit_cast(int, gc);                                    \
    float d1_ = __builtin_bit_cast(float, DPPI(gi_, 9));                      \
    float d2_ = __builtin_bit_cast(float, DPPI(gi_, 82));                     \
    float a_ = fmaf(wA, gc, qe);                                              \
    a_ = fmaf(wB, d1_, a_);                                                   \
    a_ = fmaf(wC, d2_, a_);                                                   \
    float m_ = (a_ * a_) * NL2E;                                              \
    float e_ = __builtin_amdgcn_exp2f(m_);                                    \
    float z_ = (-fabsf(a_)) * e_;            /* parallel path */              \
    float dd_ = fmaf(PPW, fabsf(a_), 1.0f);                                   \
    float r_ = __builtin_amdgcn_rcpf(dd_);                                    \
    float c01_ = fmaf(B2c, r_, B1c);                                          \
    float c23_ = fmaf(B4c, r_, B3c);                                          \
    float rr_ = r_ * r_;                                                      \
    float r4_ = rr_ * rr_;                                                    \
    float p_ = fmaf(c23_, rr_, c01_);                                         \
    p_ = fmaf(B5c, r4_, p_);                                                  \
    float pr_ = p_ * r_;                                                      \
    gc = fmaf(pr_, z_, fmaxf(a_, 0.0f));     /* g_t */                        \
    float s_ = gc + u;                        /* s_t, off-chain */            \
    ST1(s_, oc, F);                                                           \
    qe = qn_;                                                                 \
} while (0)

// one group = 9 steps; 9 asm stores; oc bumps 9 rows per 3 steps
#define COMPUTE_GRP(P) do {                                                   \
    GSTEP(0, P##0); GSTEP(768, P##1); GSTEP(1536, P##2);  oc += 9 * FDIM;     \
    GSTEP(0, P##3); GSTEP(768, P##4); GSTEP(1536, P##5);  oc += 9 * FDIM;     \
    GSTEP(0, P##6); GSTEP(768, P##7); GSTEP(1536, P##8);  oc += 9 * FDIM;     \
} while (0)

__global__ __launch_bounds__(64, 1) void scan_kernel(
    const float* __restrict__ x,
    const float* __restrict__ w,
    const float* __restrict__ bias,
    float* __restrict__ out)
{
    const int lane = threadIdx.x;
    const int g  = lane >> 2;                    // chain within wave (0..15)
    const int pr = lane & 3;
    const int p  = pr < 3 ? pr : 2;              // channel; lane3 mirrors ch2

    // XCD-pair swizzle: B = x + 8h + 16j; pair index i = 8j + x; h = f-half.
    // Both halves of a 128B line have the same (B mod 8) -> same XCD L2.
    const int B = blockIdx.x;
    const int xs = B & 7, h = (B >> 3) & 1, j = B >> 4;
    const int i = j * 8 + xs;                    // 0..255
    const int b = i >> 1;                        // 0..127
    const int fq = ((i & 1) << 1) | h;           // 0..3 (16-f quarter)
    const int f = (fq << 4) + g;

    // per-lane weight row: a = wA*s_p + wB*s_{p+1} + wC*s_{p+2} + q
    const int p1 = (p + 1) == 3 ? 0 : p + 1;
    const int p2 = (p + 2) >= 3 ? p - 1 : p + 2;
    float wA = w[p * 3 + p];
    float wB = w[p * 3 + p1];
    float wC = w[p * 3 + p2];
    float q  = bias[p];

    const float* __restrict__ xp = x   + (size_t)b * (SEQ * FDIM) + (size_t)p * FDIM + f;
    float*       __restrict__ op = out + (size_t)b * (SEQ * FDIM) + (size_t)p * FDIM + f;

    // head: plain loads, consumed by a touch HERE so the compiler's own
    // waitcnt lands before any asm vmem is outstanding.
    float gc = xp[0];                            // s_0 (head state, row p)
    asm volatile("" : "+v"(gc), "+v"(wA), "+v"(wB), "+v"(wC), "+v"(q));
    ST1(gc, op, 0);                              // head copy (1 asm store)
    float qe = q;                                // a_1 = W*s_0 + q exactly

    const float* xc = xp + 3 * FDIM;             // first u for this channel
    float*       oc = op + 3 * FDIM;

    DECL9(LA); DECL9(LB);                        // load double-buffer

    PF9(LA);                                     // g0
    PF9(LB);                                     // g1
    // outstanding: hst(1) + LA(9) + LB(9) = 19 -> vmcnt(9) retires hst+LA
    WAITVM(9, LA);

    // loop t: computes g=2t (LA) and g=2t+1 (LB); prefetches 2t+2, 2t+3
    #pragma unroll 1
    for (int t = 0; t < 54; ++t) {
        COMPUTE_GRP(LA);        // g = 2t      (9 stores)
        PF9(LA);                // g = 2t+2    (9 loads)
        // young 18 = st(2t)(9) + LA(2t+2)(9) -> LB(2t+1) ready
        WAITVM(18, LB);
        COMPUTE_GRP(LB);        // g = 2t+1
        PF9(LB);                // g = 2t+3
        WAITVM(18, LA);         // LA(2t+2) ready
    }

    // epilogue: g108 (in LA), g109 (in LB), g110
    COMPUTE_GRP(LA);            // g108
    PF9(LA);                    // g110
    WAITVM(18, LB);             // LB = g109 ready
    COMPUTE_GRP(LB);            // g109
    WAITVM(9, LA);              // young 9 = st(g109) -> LA = g110 ready
    COMPUTE_GRP(LA);            // g110
}

extern "C" void kernel_launch(void* const* d_in, const int* in_sizes, int n_in,
                              void* d_out, int out_size, void* d_ws, size_t ws_size,
                              hipStream_t stream) {
    const float* x    = (const float*)d_in[0];
    const float* w    = (const float*)d_in[1];
    const float* bias = (const float*)d_in[2];
    float* out        = (float*)d_out;

    hipLaunchKernelGGL(scan_kernel, dim3(512), dim3(64), 0, stream,
                       x, w, bias, out);
}

// Round 11
// 60.987 us; speedup vs baseline: 1.1858x; 1.1858x over previous
//
#include <hip/hip_runtime.h>
#include <math.h>

#define SEQ   3000
#define FDIM  64
// 999 steps = 111 groups (g0..g110) x 9 steps. Channel-parallel quads (R9):
// lane p of each quad computes channel p of one (b,f) chain; lane 3 mirrors
// ch2. R11: the whole step body is HAND-SCHEDULED inline asm so every chain
// dep hop is separated by independent work (dpp pair, exp path, relu, the
// per-step prefetch load, the store). Triple-buffered loads: during group g
// each step issues 1 load for group g+2 (reuse distance 2 groups); one
// s_waitcnt vmcnt(18) per group boundary, never 0 in the loop.

#define PPWc  0.23164189f                  // 0.3275911 / sqrt(2)
#define B1f   0.127414796f                 // 0.5*0.254829592
#define B2f   (-0.142248368f)              // 0.5*-0.284496736
#define B3f   0.7107068705f                // 0.5*1.421413741
#define B4f   (-0.7265760135f)             // 0.5*-1.453152027
#define B5f   0.5307027145f                // 0.5*1.061405429
#define NL2Ef (-0.72134752044448170368f)   // -0.5*log2(e)

#define DECL9(p) float p##0,p##1,p##2,p##3,p##4,p##5,p##6,p##7,p##8
#define TOUCH9(P) "+v"(P##0),"+v"(P##1),"+v"(P##2),"+v"(P##3),"+v"(P##4),     \
    "+v"(P##5),"+v"(P##6),"+v"(P##7),"+v"(P##8)

// prefetch 1 value via SGPR base + per-lane constant voffset
#define PF1S(dst, OFF) asm volatile(                                          \
    "global_load_dword %0, %1, %2 offset:" #OFF                               \
    : "=v"(dst) : "v"(voff), "s"(lbase) : "memory")

#define WAITVM(Nlit, P) do {                                                  \
    asm volatile("s_waitcnt vmcnt(" #Nlit ")" : TOUCH9(P) : : "memory");      \
    __builtin_amdgcn_sched_barrier(0);                                        \
} while (0)

// --- chain head: matvec + exp/rcp launches, scheduled with fillers ---
// chain: s -> a(fma/fmac/fmac) -> dd -> rcp ; off-chain: dpp x2, t2, m, exp,
// relu interleave into the hops. DPP reads s 3+ instrs after its write.
#define ASMA() asm volatile(                                                  \
    "v_fma_f32 %[a], %[wa], %[s], %[q]\n\t"                                   \
    "v_mov_b32_dpp %[d1], %[s] quad_perm:[1,2,0,0] row_mask:0xf bank_mask:0xf\n\t" \
    "v_mov_b32_dpp %[d2], %[s] quad_perm:[2,0,1,1] row_mask:0xf bank_mask:0xf\n\t" \
    "v_fmac_f32 %[a], %[wb], %[d1]\n\t"                                       \
    "v_fmac_f32 %[a], %[wc], %[d2]\n\t"                                       \
    "v_mul_f32 %[t2], %[a], %[a]\n\t"                                         \
    "v_max_f32 %[rl], 0, %[a]\n\t"                                            \
    "v_fma_f32 %[dd], %[ppw], abs(%[a]), 1.0\n\t"                             \
    "v_mul_f32 %[m], %[t2], %[nl2e]\n\t"                                      \
    "v_rcp_f32 %[r], %[dd]\n\t"                                               \
    "v_exp_f32 %[e], %[m]"                                                    \
    : [a]"=&v"(a_), [d1]"=&v"(d1_), [d2]"=&v"(d2_), [t2]"=&v"(t2_),           \
      [dd]"=&v"(dd_), [m]"=&v"(m_), [r]"=&v"(r_), [e]"=&v"(e_), [rl]"=&v"(rl_)\
    : [s]"v"(s), [wa]"v"(wA), [wb]"v"(wB), [wc]"v"(wC), [q]"v"(q),            \
      [ppw]"v"(cPPW), [nl2e]"v"(cNL2E))

// --- rational tail + new state + store (store also spaces s-write -> next
// step's DPP read by 2+ instructions) ---
#define ASMB(U, OFF) asm volatile(                                            \
    "v_fma_f32 %[c01], %[b2], %[r], %[b1]\n\t"                                \
    "v_fma_f32 %[c23], %[b4], %[r], %[b3]\n\t"                                \
    "v_mul_f32 %[rr], %[r], %[r]\n\t"                                         \
    "v_mul_f32 %[z], -abs(%[a]), %[e]\n\t"                                    \
    "v_add_f32 %[rlu], %[rl], %[u]\n\t"                                       \
    "v_fma_f32 %[pp], %[c23], %[rr], %[c01]\n\t"                              \
    "v_mul_f32 %[r4], %[rr], %[rr]\n\t"                                       \
    "v_fmac_f32 %[pp], %[b5], %[r4]\n\t"                                      \
    "v_mul_f32 %[pr], %[pp], %[r]\n\t"                                        \
    "v_fma_f32 %[s], %[pr], %[z], %[rlu]\n\t"                                 \
    "global_store_dword %[vo], %[s], %[ob] offset:" #OFF                      \
    : [s]"=&v"(s), [c01]"=&v"(c01_), [c23]"=&v"(c23_), [rr]"=&v"(rr_),        \
      [r4]"=&v"(r4_), [pp]"=&v"(pp_), [pr]"=&v"(pr_), [z]"=&v"(z_),           \
      [rlu]"=&v"(rlu_)                                                        \
    : [a]"v"(a_), [r]"v"(r_), [e]"v"(e_), [rl]"v"(rl_), [u]"v"(U),            \
      [b1]"v"(cB1), [b2]"v"(cB2), [b3]"v"(cB3), [b4]"v"(cB4), [b5]"v"(cB5),   \
      [vo]"v"(voff), [ob]"s"(obase)                                           \
    : "memory")

#define STEP_LD(U, LD, OFF)  do { ASMA(); PF1S(LD, OFF); ASMB(U, OFF); } while (0)
#define STEP_NOLD(U, OFF)    do { ASMA(); ASMB(U, OFF); } while (0)

// one group = 9 steps; loads target buffer L (group g+2); bases bump 2304 B
// (576 floats) every 3 steps so all offset immediates stay in {0,768,1536}.
#define GRP_LD(P, L) do {                                                     \
    STEP_LD(P##0, L##0, 0); STEP_LD(P##1, L##1, 768); STEP_LD(P##2, L##2, 1536);\
    lbase += 576; obase += 576;                                               \
    STEP_LD(P##3, L##3, 0); STEP_LD(P##4, L##4, 768); STEP_LD(P##5, L##5, 1536);\
    lbase += 576; obase += 576;                                               \
    STEP_LD(P##6, L##6, 0); STEP_LD(P##7, L##7, 768); STEP_LD(P##8, L##8, 1536);\
    lbase += 576; obase += 576;                                               \
} while (0)

#define GRP_NOLD(P) do {                                                      \
    STEP_NOLD(P##0, 0); STEP_NOLD(P##1, 768); STEP_NOLD(P##2, 1536);          \
    obase += 576;                                                             \
    STEP_NOLD(P##3, 0); STEP_NOLD(P##4, 768); STEP_NOLD(P##5, 1536);          \
    obase += 576;                                                             \
    STEP_NOLD(P##6, 0); STEP_NOLD(P##7, 768); STEP_NOLD(P##8, 1536);          \
    obase += 576;                                                             \
} while (0)

// prologue batched loads (one group)
#define PF3B(Pa, Pb, Pc) do {                                                 \
    PF1S(Pa, 0); PF1S(Pb, 768); PF1S(Pc, 1536); lbase += 576;                 \
} while (0)
#define PF9B(P) do { PF3B(P##0,P##1,P##2); PF3B(P##3,P##4,P##5);              \
    PF3B(P##6,P##7,P##8); } while (0)

__global__ __launch_bounds__(64, 1) void scan_kernel(
    const float* __restrict__ x,
    const float* __restrict__ w,
    const float* __restrict__ bias,
    float* __restrict__ out)
{
    const int lane = threadIdx.x;
    const int g  = lane >> 2;                    // chain within wave (0..15)
    const int pr = lane & 3;
    const int p  = pr < 3 ? pr : 2;              // channel; lane3 mirrors ch2

    // XCD-pair swizzle (R10, verified: FETCH 96->48 MB): both halves of each
    // 128B line land on blocks with equal (blockIdx mod 8) -> same XCD L2.
    const int B = blockIdx.x;
    const int xs = B & 7, h = (B >> 3) & 1, j = B >> 4;
    const int i = j * 8 + xs;                    // 0..255
    const int b = i >> 1;                        // 0..127
    const int fq = ((i & 1) << 1) | h;           // 0..3 (16-f quarter)
    const int f = (fq << 4) + g;

    const int p1i = (p + 1) == 3 ? 0 : p + 1;
    const int p2i = (p + 2) >= 3 ? p - 1 : p + 2;
    float wA = w[p * 3 + p];
    float wB = w[p * 3 + p1i];
    float wC = w[p * 3 + p2i];
    float q  = bias[p];

    // constants in VGPRs (VOP3 forbids literals; 0/1.0 stay inline)
    float cPPW = PPWc, cNL2E = NL2Ef;
    float cB1 = B1f, cB2 = B2f, cB3 = B3f, cB4 = B4f, cB5 = B5f;

    // per-lane constant byte offset (channel row + f); bases are uniform SGPRs
    const int voff = p * 256 + f * 4;
    const float* lbase = x   + (size_t)b * (SEQ * FDIM) + 3 * FDIM;  // row 3
    float*       obase = out + (size_t)b * (SEQ * FDIM) + 3 * FDIM;  // row 3
    const float* hbase = x   + (size_t)b * (SEQ * FDIM);             // row 0
    float*       ohead = out + (size_t)b * (SEQ * FDIM);

    // head: plain load of s0, touch so compiler's waitcnt lands before any
    // asm loads are outstanding; asm store of the head copy.
    float s = *(const float*)((const char*)hbase + voff);
    asm volatile("" : "+v"(s), "+v"(wA), "+v"(wB), "+v"(wC), "+v"(q),
                      "+v"(cPPW), "+v"(cNL2E), "+v"(cB1), "+v"(cB2),
                      "+v"(cB3), "+v"(cB4), "+v"(cB5));
    asm volatile("global_store_dword %0, %1, %2"
                 :: "v"(voff), "v"(s), "s"(ohead) : "memory");

    float a_, d1_, d2_, t2_, dd_, m_, r_, e_, rl_;
    float c01_, c23_, rr_, r4_, pp_, pr_, z_, rlu_;

    DECL9(LA); DECL9(LB); DECL9(LC);             // triple buffer

    PF9B(LA);                                    // g0
    PF9B(LB);                                    // g1
    // outstanding: hst(1)+18 -> vmcnt(9) retires hst+LA; LB stays in flight
    WAITVM(9, LA);

    // 36 iters x 3 groups: g0..g107. During group g (buffer X) issue loads
    // for g+2 into the buffer consumed at g-1 (fully dead -> no WAR race).
    #pragma unroll 1
    for (int t = 0; t < 36; ++t) {
        GRP_LD(LA, LC);   WAITVM(18, LB);        // g=3t   ; ld g+2 -> C
        GRP_LD(LB, LA);   WAITVM(18, LC);        // g=3t+1 ; ld g+3 -> A
        GRP_LD(LC, LB);   WAITVM(18, LA);        // g=3t+2 ; ld g+4 -> B
    }

    // epilogue: g108 (A, loads g110->C), g109 (B, no loads), g110 (C)
    GRP_LD(LA, LC);       WAITVM(18, LB);        // g108; LB=g109 ready
    GRP_NOLD(LB);         WAITVM(9,  LC);        // g109; LC=g110 ready
    GRP_NOLD(LC);                                // g110
}

extern "C" void kernel_launch(void* const* d_in, const int* in_sizes, int n_in,
                              void* d_out, int out_size, void* d_ws, size_t ws_size,
                              hipStream_t stream) {
    const float* x    = (const float*)d_in[0];
    const float* w    = (const float*)d_in[1];
    const float* bias = (const float*)d_in[2];
    float* out        = (float*)d_out;

    hipLaunchKernelGGL(scan_kernel, dim3(512), dim3(64), 0, stream,
                       x, w, bias, out);
}